// Round 1
// baseline (421.178 us; speedup 1.0000x reference)
//
#include <hip/hip_runtime.h>
#include <stdint.h>

typedef int v4i __attribute__((ext_vector_type(4)));

#define M_TOK 8192
#define N_OUT 4096
#define K_IN  4096

// -------------------------------------------------------------------------
// Pack int32 carriers (values in [-128,127]) into contiguous int8.
// Each thread: 4x int4 loads (64B) -> 1x int4 store (16 packed int8 x4).
// -------------------------------------------------------------------------
__global__ __launch_bounds__(256) void pack_int32_to_int8(
    const int4* __restrict__ src, int4* __restrict__ dst, int n16)
{
    int i = blockIdx.x * blockDim.x + threadIdx.x;
    if (i >= n16) return;
    int4 a = src[4 * i + 0];
    int4 b = src[4 * i + 1];
    int4 c = src[4 * i + 2];
    int4 d = src[4 * i + 3];
    int4 p;
    p.x = (a.x & 255) | ((a.y & 255) << 8) | ((a.z & 255) << 16) | ((a.w & 255) << 24);
    p.y = (b.x & 255) | ((b.y & 255) << 8) | ((b.z & 255) << 16) | ((b.w & 255) << 24);
    p.z = (c.x & 255) | ((c.y & 255) << 8) | ((c.z & 255) << 16) | ((c.w & 255) << 24);
    p.w = (d.x & 255) | ((d.y & 255) << 8) | ((d.z & 255) << 16) | ((d.w & 255) << 24);
    dst[i] = p;
}

// -------------------------------------------------------------------------
// i8 GEMM: C[M,N] = A[M,K] . B[N,K]^T, int32 accumulate, fused
// rescale/round/clip epilogue, float output.
// 128x128 tile, BK=64, 4 waves (2x2), each wave 4x4 of mfma_i32_16x16x64_i8.
// m97 structure: global_load_lds width=16 staging, 2-barrier K-loop.
// -------------------------------------------------------------------------
__global__ __launch_bounds__(256) void gemm_i8_kernel(
    const char* __restrict__ A8,      // [M][K] int8 row-major
    const char* __restrict__ B8,      // [N][K] int8 row-major
    const float* __restrict__ scale_ptr,
    float* __restrict__ out)          // [M][N] float + 1 scalar at end
{
    __shared__ alignas(16) char lA[128 * 64];   // 8 KB
    __shared__ alignas(16) char lB[128 * 64];   // 8 KB

    const int tid  = threadIdx.x;
    const int wave = tid >> 6;
    const int lane = tid & 63;

    const int bm = blockIdx.y * 128;
    const int bn = blockIdx.x * 128;

    const int wm = (wave >> 1) * 64;   // wave row offset within tile
    const int wn = (wave & 1) * 64;    // wave col offset within tile

    v4i acc[4][4];
#pragma unroll
    for (int i = 0; i < 4; ++i)
#pragma unroll
        for (int j = 0; j < 4; ++j)
            acc[i][j] = (v4i){0, 0, 0, 0};

    // ---- staging geometry: one wave-load = 64 lanes x 16B = 1KB = 16 rows
    // of 64 bytes. 8 chunks per operand tile; wave w stages chunks {2w, 2w+1}.
    const int srow = lane >> 2;          // 0..15 row within chunk
    const int scol = (lane & 3) * 16;    // 0/16/32/48 byte offset in row
    const int ca0  = wave * 2;

    const char* gA0 = A8 + (size_t)(bm + ca0 * 16 + srow) * K_IN + scol;
    const char* gA1 = A8 + (size_t)(bm + ca0 * 16 + 16 + srow) * K_IN + scol;
    const char* gB0 = B8 + (size_t)(bn + ca0 * 16 + srow) * K_IN + scol;
    const char* gB1 = B8 + (size_t)(bn + ca0 * 16 + 16 + srow) * K_IN + scol;

    char* lA0 = lA + ca0 * 1024;
    char* lA1 = lA + (ca0 + 1) * 1024;
    char* lB0 = lB + ca0 * 1024;
    char* lB1 = lB + (ca0 + 1) * 1024;

    // ---- fragment geometry (verified 16x16 analog):
    // A frag: m = lane&15, k bytes = (lane>>4)*16 .. +15  -> ds_read_b128
    const int fm    = lane & 15;
    const int fquad = (lane >> 4) * 16;

    for (int k0 = 0; k0 < K_IN; k0 += 64) {
        __builtin_amdgcn_global_load_lds(
            (const __attribute__((address_space(1))) void*)(gA0 + k0),
            (__attribute__((address_space(3))) void*)lA0, 16, 0, 0);
        __builtin_amdgcn_global_load_lds(
            (const __attribute__((address_space(1))) void*)(gA1 + k0),
            (__attribute__((address_space(3))) void*)lA1, 16, 0, 0);
        __builtin_amdgcn_global_load_lds(
            (const __attribute__((address_space(1))) void*)(gB0 + k0),
            (__attribute__((address_space(3))) void*)lB0, 16, 0, 0);
        __builtin_amdgcn_global_load_lds(
            (const __attribute__((address_space(1))) void*)(gB1 + k0),
            (__attribute__((address_space(3))) void*)lB1, 16, 0, 0);

        __syncthreads();   // drain vmcnt: staging visible to all waves

        v4i af[4], bf[4];
#pragma unroll
        for (int i = 0; i < 4; ++i)
            af[i] = *(const v4i*)(lA + (wm + i * 16 + fm) * 64 + fquad);
#pragma unroll
        for (int j = 0; j < 4; ++j)
            bf[j] = *(const v4i*)(lB + (wn + j * 16 + fm) * 64 + fquad);

#pragma unroll
        for (int i = 0; i < 4; ++i)
#pragma unroll
            for (int j = 0; j < 4; ++j)
                acc[i][j] = __builtin_amdgcn_mfma_i32_16x16x64_i8(
                    af[i], bf[j], acc[i][j], 0, 0, 0);

        __syncthreads();   // LDS reads done before next staging overwrites
    }

    // ---- epilogue: y = clip(rint(acc * scale), -128, 127) as float
    const float s     = scale_ptr[0];
    const float scale = (s * 0.1f) / 0.1f;   // match ref op order
    const int rowg = (lane >> 4) * 4;
    const int coll = lane & 15;

#pragma unroll
    for (int i = 0; i < 4; ++i) {
#pragma unroll
        for (int j = 0; j < 4; ++j) {
#pragma unroll
            for (int r = 0; r < 4; ++r) {
                int row = bm + wm + i * 16 + rowg + r;
                int col = bn + wn + j * 16 + coll;
                float y = (float)acc[i][j][r] * scale;
                y = rintf(y);                       // round half-to-even, like jnp.round
                y = fminf(fmaxf(y, -128.0f), 127.0f);
                out[(size_t)row * N_OUT + col] = y;
            }
        }
    }

    // second tuple element: OUT_SCALE
    if (bm == 0 && bn == 0 && tid == 0)
        out[(size_t)M_TOK * N_OUT] = 0.1f;
}

// -------------------------------------------------------------------------
extern "C" void kernel_launch(void* const* d_in, const int* in_sizes, int n_in,
                              void* d_out, int out_size, void* d_ws, size_t ws_size,
                              hipStream_t stream)
{
    const int*   x_q     = (const int*)d_in[0];   // [8192*4096] int32 carriers
    const int*   w_q     = (const int*)d_in[1];   // [4096*4096] int32 carriers
    const float* scale_x = (const float*)d_in[2]; // 1 element
    float* out = (float*)d_out;

    char* A8 = (char*)d_ws;                              // 32 MB
    char* B8 = (char*)d_ws + (size_t)M_TOK * K_IN;       // 16 MB

    const int n16x = (M_TOK * K_IN) / 16;   // 2097152
    const int n16w = (N_OUT * K_IN) / 16;   // 1048576

    pack_int32_to_int8<<<n16x / 256, 256, 0, stream>>>(
        (const int4*)x_q, (int4*)A8, n16x);
    pack_int32_to_int8<<<n16w / 256, 256, 0, stream>>>(
        (const int4*)w_q, (int4*)B8, n16w);

    dim3 grid(N_OUT / 128, M_TOK / 128);   // 32 x 64 = 2048 blocks
    gemm_i8_kernel<<<grid, 256, 0, stream>>>(A8, B8, scale_x, out);
}

// Round 2
// 416.848 us; speedup vs baseline: 1.0104x; 1.0104x over previous
//
#include <hip/hip_runtime.h>
#include <stdint.h>

typedef int v4i __attribute__((ext_vector_type(4)));

#define M_TOK 8192
#define N_OUT 4096
#define K_IN  4096

// -------------------------------------------------------------------------
// Pack int32 carriers (values in [-128,127]) into contiguous int8.
// Fully coalesced: lane reads one int4 (16B contiguous across lanes),
// writes one packed int (4B contiguous across lanes).
// -------------------------------------------------------------------------
__global__ __launch_bounds__(256) void pack_int32_to_int8(
    const int4* __restrict__ src, int* __restrict__ dst, int n4)
{
    int i = blockIdx.x * blockDim.x + threadIdx.x;
    if (i >= n4) return;
    int4 a = src[i];
    dst[i] = (a.x & 255) | ((a.y & 255) << 8) | ((a.z & 255) << 16) | ((a.w & 255) << 24);
}

// -------------------------------------------------------------------------
// i8 GEMM: C[M,N] = A[M,K] . B[N,K]^T, int32 accumulate, fused
// rescale/round/clip epilogue, float output.
// 128x128 tile, BK=64, 4 waves (2x2), each wave 4x4 of mfma_i32_16x16x64_i8.
// m97 structure: global_load_lds width=16 staging, 2-barrier K-loop.
// Measured R1: 178 us, MfmaUtil 34.7%, 39% of i8 ubench ceiling.
// -------------------------------------------------------------------------
__global__ __launch_bounds__(256) void gemm_i8_kernel(
    const char* __restrict__ A8,      // [M][K] int8 row-major
    const char* __restrict__ B8,      // [N][K] int8 row-major
    const float* __restrict__ scale_ptr,
    float* __restrict__ out)          // [M][N] float + 1 scalar at end
{
    __shared__ alignas(16) char lA[128 * 64];   // 8 KB
    __shared__ alignas(16) char lB[128 * 64];   // 8 KB

    const int tid  = threadIdx.x;
    const int wave = tid >> 6;
    const int lane = tid & 63;

    const int bm = blockIdx.y * 128;
    const int bn = blockIdx.x * 128;

    const int wm = (wave >> 1) * 64;   // wave row offset within tile
    const int wn = (wave & 1) * 64;    // wave col offset within tile

    v4i acc[4][4];
#pragma unroll
    for (int i = 0; i < 4; ++i)
#pragma unroll
        for (int j = 0; j < 4; ++j)
            acc[i][j] = (v4i){0, 0, 0, 0};

    // ---- staging geometry: one wave-load = 64 lanes x 16B = 1KB = 16 rows
    // of 64 bytes. 8 chunks per operand tile; wave w stages chunks {2w, 2w+1}.
    const int srow = lane >> 2;          // 0..15 row within chunk
    const int scol = (lane & 3) * 16;    // 0/16/32/48 byte offset in row
    const int ca0  = wave * 2;

    const char* gA0 = A8 + (size_t)(bm + ca0 * 16 + srow) * K_IN + scol;
    const char* gA1 = A8 + (size_t)(bm + ca0 * 16 + 16 + srow) * K_IN + scol;
    const char* gB0 = B8 + (size_t)(bn + ca0 * 16 + srow) * K_IN + scol;
    const char* gB1 = B8 + (size_t)(bn + ca0 * 16 + 16 + srow) * K_IN + scol;

    char* lA0 = lA + ca0 * 1024;
    char* lA1 = lA + (ca0 + 1) * 1024;
    char* lB0 = lB + ca0 * 1024;
    char* lB1 = lB + (ca0 + 1) * 1024;

    // ---- fragment geometry:
    // A frag: m = lane&15, k bytes = (lane>>4)*16 .. +15  -> ds_read_b128
    const int fm    = lane & 15;
    const int fquad = (lane >> 4) * 16;

    for (int k0 = 0; k0 < K_IN; k0 += 64) {
        __builtin_amdgcn_global_load_lds(
            (const __attribute__((address_space(1))) void*)(gA0 + k0),
            (__attribute__((address_space(3))) void*)lA0, 16, 0, 0);
        __builtin_amdgcn_global_load_lds(
            (const __attribute__((address_space(1))) void*)(gA1 + k0),
            (__attribute__((address_space(3))) void*)lA1, 16, 0, 0);
        __builtin_amdgcn_global_load_lds(
            (const __attribute__((address_space(1))) void*)(gB0 + k0),
            (__attribute__((address_space(3))) void*)lB0, 16, 0, 0);
        __builtin_amdgcn_global_load_lds(
            (const __attribute__((address_space(1))) void*)(gB1 + k0),
            (__attribute__((address_space(3))) void*)lB1, 16, 0, 0);

        __syncthreads();   // drain vmcnt: staging visible to all waves

        v4i af[4], bf[4];
#pragma unroll
        for (int i = 0; i < 4; ++i)
            af[i] = *(const v4i*)(lA + (wm + i * 16 + fm) * 64 + fquad);
#pragma unroll
        for (int j = 0; j < 4; ++j)
            bf[j] = *(const v4i*)(lB + (wn + j * 16 + fm) * 64 + fquad);

#pragma unroll
        for (int i = 0; i < 4; ++i)
#pragma unroll
            for (int j = 0; j < 4; ++j)
                acc[i][j] = __builtin_amdgcn_mfma_i32_16x16x64_i8(
                    af[i], bf[j], acc[i][j], 0, 0, 0);

        __syncthreads();   // LDS reads done before next staging overwrites
    }

    // ---- epilogue: y = clip(rint(acc * scale), -128, 127) as float
    const float s     = scale_ptr[0];
    const float scale = (s * 0.1f) / 0.1f;   // match ref op order
    const int rowg = (lane >> 4) * 4;
    const int coll = lane & 15;

#pragma unroll
    for (int i = 0; i < 4; ++i) {
#pragma unroll
        for (int j = 0; j < 4; ++j) {
#pragma unroll
            for (int r = 0; r < 4; ++r) {
                int row = bm + wm + i * 16 + rowg + r;
                int col = bn + wn + j * 16 + coll;
                float y = (float)acc[i][j][r] * scale;
                y = rintf(y);                       // round half-to-even, like jnp.round
                y = fminf(fmaxf(y, -128.0f), 127.0f);
                out[(size_t)row * N_OUT + col] = y;
            }
        }
    }

    // second tuple element: OUT_SCALE
    if (bm == 0 && bn == 0 && tid == 0)
        out[(size_t)M_TOK * N_OUT] = 0.1f;
}

// -------------------------------------------------------------------------
extern "C" void kernel_launch(void* const* d_in, const int* in_sizes, int n_in,
                              void* d_out, int out_size, void* d_ws, size_t ws_size,
                              hipStream_t stream)
{
    const int*   x_q     = (const int*)d_in[0];   // [8192*4096] int32 carriers
    const int*   w_q     = (const int*)d_in[1];   // [4096*4096] int32 carriers
    const float* scale_x = (const float*)d_in[2]; // 1 element
    float* out = (float*)d_out;

    char* A8 = (char*)d_ws;                              // 32 MB
    char* B8 = (char*)d_ws + (size_t)M_TOK * K_IN;       // 16 MB

    const int n4x = (M_TOK * K_IN) / 4;   // 8388608
    const int n4w = (N_OUT * K_IN) / 4;   // 4194304

    pack_int32_to_int8<<<n4x / 256, 256, 0, stream>>>(
        (const int4*)x_q, (int*)A8, n4x);
    pack_int32_to_int8<<<n4w / 256, 256, 0, stream>>>(
        (const int4*)w_q, (int*)B8, n4w);

    dim3 grid(N_OUT / 128, M_TOK / 128);   // 32 x 64 = 2048 blocks
    gemm_i8_kernel<<<grid, 256, 0, stream>>>(A8, B8, scale_x, out);
}

// Round 3
// 400.762 us; speedup vs baseline: 1.0509x; 1.0401x over previous
//
#include <hip/hip_runtime.h>
#include <stdint.h>

typedef int v4i  __attribute__((ext_vector_type(4)));
typedef int v16i __attribute__((ext_vector_type(16)));

#define M_TOK 8192
#define N_OUT 4096
#define K_IN  4096

// -------------------------------------------------------------------------
// Pack both int32-carrier tensors into int8 in one dispatch.
// Coalesced: lane reads one int4 (16B), writes one packed int (4B).
// -------------------------------------------------------------------------
__device__ __forceinline__ int pack4(int4 a) {
    return (a.x & 255) | ((a.y & 255) << 8) | ((a.z & 255) << 16) | ((a.w & 255) << 24);
}

__global__ __launch_bounds__(256) void pack_both(
    const int4* __restrict__ x, const int4* __restrict__ w,
    int* __restrict__ dA, int* __restrict__ dB, int n4x, int n4w)
{
    int i = blockIdx.x * blockDim.x + threadIdx.x;
    if (i < n4x) {
        dA[i] = pack4(x[i]);
    } else {
        int j = i - n4x;
        if (j < n4w) dB[j] = pack4(w[j]);
    }
}

// -------------------------------------------------------------------------
// i8 GEMM: C[M,N] = A[M,K] . B[N,K]^T, int32 accumulate, fused epilogue.
// 128x128 tile, BK=128 (32 KB LDS), 4 waves (2x2), each wave 64x64 as
// 2x2 of mfma_i32_32x32x32_i8 (16 acc regs each).
// LDS rows are 128 B (= 32 banks): XOR-swizzle on the GLOBAL fetch side
// (global_load_lds lands at fixed base+lane*16, so the swizzle must be
// applied to the source address): LDS[r][c16] = global[r][c16 ^ (r&7)].
// R1 history: BK=64 / 16x16x64 = 178 us, MfmaUtil 34.7% (m97 plateau).
// -------------------------------------------------------------------------
__global__ __launch_bounds__(256) void gemm_i8_kernel(
    const char* __restrict__ A8,      // [M][K] int8 row-major
    const char* __restrict__ B8,      // [N][K] int8 row-major
    const float* __restrict__ scale_ptr,
    float* __restrict__ out)          // [M][N] float + 1 scalar at end
{
    __shared__ alignas(16) char lA[128 * 128];   // 16 KB
    __shared__ alignas(16) char lB[128 * 128];   // 16 KB

    const int tid  = threadIdx.x;
    const int wave = tid >> 6;
    const int lane = tid & 63;

    const int bm = blockIdx.y * 128;
    const int bn = blockIdx.x * 128;

    const int wm = (wave >> 1) * 64;   // wave row offset within tile
    const int wn = (wave & 1) * 64;    // wave col offset within tile

    v16i acc[2][2];
#pragma unroll
    for (int i = 0; i < 2; ++i)
#pragma unroll
        for (int j = 0; j < 2; ++j)
#pragma unroll
            for (int r = 0; r < 16; ++r)
                acc[i][j][r] = 0;

    // ---- staging geometry: one wave-load = 64 lanes x 16B = 1KB = 8 rows
    // of 128 B. Wave w stages rows [32w, 32w+32) of each operand tile via
    // 4 chunks. Global column granule is XOR-swizzled by row&7.
    const int srow = lane >> 3;                     // 0..7 row within chunk
    const int scol = ((lane & 7) ^ srow) << 4;      // swizzled byte offset

    const char* gA[4]; const char* gB[4];
    char* lAp[4]; char* lBp[4];
#pragma unroll
    for (int q = 0; q < 4; ++q) {
        int row0 = wave * 32 + q * 8;
        gA[q] = A8 + (size_t)(bm + row0 + srow) * K_IN + scol;
        gB[q] = B8 + (size_t)(bn + row0 + srow) * K_IN + scol;
        lAp[q] = lA + row0 * 128;
        lBp[q] = lB + row0 * 128;
    }

    // ---- fragment geometry (32x32x32 i8):
    // A[m = lane&31][k = (lane>>5)*16 + j], 16 bytes -> ds_read_b128
    const int fm = lane & 31;
    const int fh = lane >> 5;       // 0/1
    const int fsw = fm & 7;         // row&7 for the read-side unswizzle

    for (int k0 = 0; k0 < K_IN; k0 += 128) {
#pragma unroll
        for (int q = 0; q < 4; ++q) {
            __builtin_amdgcn_global_load_lds(
                (const __attribute__((address_space(1))) void*)(gA[q] + k0),
                (__attribute__((address_space(3))) void*)lAp[q], 16, 0, 0);
            __builtin_amdgcn_global_load_lds(
                (const __attribute__((address_space(1))) void*)(gB[q] + k0),
                (__attribute__((address_space(3))) void*)lBp[q], 16, 0, 0);
        }

        __syncthreads();   // staging visible to all waves

#pragma unroll
        for (int kk = 0; kk < 4; ++kk) {
            const int goff = ((kk * 2 + fh) ^ fsw) << 4;   // swizzled granule
            v4i af[2], bf[2];
#pragma unroll
            for (int t = 0; t < 2; ++t) {
                af[t] = *(const v4i*)(lA + (wm + t * 32 + fm) * 128 + goff);
                bf[t] = *(const v4i*)(lB + (wn + t * 32 + fm) * 128 + goff);
            }
#pragma unroll
            for (int ti = 0; ti < 2; ++ti)
#pragma unroll
                for (int tj = 0; tj < 2; ++tj)
                    acc[ti][tj] = __builtin_amdgcn_mfma_i32_32x32x32_i8(
                        af[ti], bf[tj], acc[ti][tj], 0, 0, 0);
        }

        __syncthreads();   // LDS reads done before next staging overwrites
    }

    // ---- epilogue: y = clip(rint(acc * scale), -128, 127) as float
    // 32x32 C/D layout: col = lane&31, row = (reg&3) + 8*(reg>>2) + 4*(lane>>5)
    const float s     = scale_ptr[0];
    const float scale = (s * 0.1f) / 0.1f;   // match ref op order

#pragma unroll
    for (int ti = 0; ti < 2; ++ti) {
#pragma unroll
        for (int tj = 0; tj < 2; ++tj) {
#pragma unroll
            for (int r = 0; r < 16; ++r) {
                int row = bm + wm + ti * 32 + (r & 3) + 8 * (r >> 2) + 4 * fh;
                int col = bn + wn + tj * 32 + fm;
                float y = (float)acc[ti][tj][r] * scale;
                y = rintf(y);                       // round half-to-even
                y = fminf(fmaxf(y, -128.0f), 127.0f);
                out[(size_t)row * N_OUT + col] = y;
            }
        }
    }

    // second tuple element: OUT_SCALE
    if (bm == 0 && bn == 0 && tid == 0)
        out[(size_t)M_TOK * N_OUT] = 0.1f;
}

// -------------------------------------------------------------------------
extern "C" void kernel_launch(void* const* d_in, const int* in_sizes, int n_in,
                              void* d_out, int out_size, void* d_ws, size_t ws_size,
                              hipStream_t stream)
{
    const int*   x_q     = (const int*)d_in[0];   // [8192*4096] int32 carriers
    const int*   w_q     = (const int*)d_in[1];   // [4096*4096] int32 carriers
    const float* scale_x = (const float*)d_in[2]; // 1 element
    float* out = (float*)d_out;

    char* A8 = (char*)d_ws;                              // 32 MB
    char* B8 = (char*)d_ws + (size_t)M_TOK * K_IN;       // 16 MB

    const int n4x = (M_TOK * K_IN) / 4;   // 8388608
    const int n4w = (N_OUT * K_IN) / 4;   // 4194304

    pack_both<<<(n4x + n4w) / 256, 256, 0, stream>>>(
        (const int4*)x_q, (const int4*)w_q, (int*)A8, (int*)B8, n4x, n4w);

    dim3 grid(N_OUT / 128, M_TOK / 128);   // 32 x 64 = 2048 blocks
    gemm_i8_kernel<<<grid, 256, 0, stream>>>(A8, B8, scale_x, out);
}